// Round 9
// baseline (60.375 us; speedup 1.0000x reference)
//
#include <hip/hip_runtime.h>
#include <cmath>

// ---------------------------------------------------------------------------
// NeighborAdjustingLoss v9: v8 + precomputed cent order-statistics.
// The per-row cent scan (16 KB read + 2x4096 fmin/fmax + rank-tail gathers)
// only produces min/max of cent over "all but k+1<=33 excluded positions".
// Since the survivor has global rank < 64, a one-block centlist_kernel
// precomputes the exact 64 smallest / 64 largest (value,idx) pairs once;
// row_loss tests them against a per-wave 4096-bit exclusion bitmap.
// Stream pass is now sim-only. Bit-identical output (min/max order-free,
// survivor guaranteed in list for k<=62). B=4096, M=8192, fp32.
// ---------------------------------------------------------------------------

#define CAPW 128   // per-wave sim-candidate capacity (E[n]~57 @ thr 2.2)
#define MAXIT 40   // u32-key bisection bound for exact fallbacks
#define NLIST 64   // cent order-statistic list length (needs k+1 < NLIST)

__device__ inline float wave_max_f(float x) {
#pragma unroll
    for (int off = 32; off > 0; off >>= 1) x = fmaxf(x, __shfl_xor(x, off, 64));
    return x;
}
__device__ inline float wave_min_f(float x) {
#pragma unroll
    for (int off = 32; off > 0; off >>= 1) x = fminf(x, __shfl_xor(x, off, 64));
    return x;
}
__device__ inline float wave_sum_f(float x) {
#pragma unroll
    for (int off = 32; off > 0; off >>= 1) x += __shfl_xor(x, off, 64);
    return x;
}
__device__ inline unsigned int wave_min_u32(unsigned int x) {
#pragma unroll
    for (int off = 32; off > 0; off >>= 1) {
        unsigned int o = (unsigned int)__shfl_xor((int)x, off, 64);
        x = (o < x) ? o : x;
    }
    return x;
}
__device__ inline unsigned int wave_max_u32(unsigned int x) {
#pragma unroll
    for (int off = 32; off > 0; off >>= 1) {
        unsigned int o = (unsigned int)__shfl_xor((int)x, off, 64);
        x = (o > x) ? o : x;
    }
    return x;
}

// order-preserving float<->uint key
__device__ inline unsigned int f_to_key(float f) {
    unsigned int u = __float_as_uint(f);
    return u ^ ((u & 0x80000000u) ? 0xFFFFFFFFu : 0x80000000u);
}
__device__ inline float key_to_f(unsigned int key) {
    unsigned int u = key ^ ((key & 0x80000000u) ? 0x80000000u : 0xFFFFFFFFu);
    return __uint_as_float(u);
}

// bits set among lanes strictly below mine
__device__ inline unsigned int lane_prefix(unsigned long long mask) {
    return __builtin_amdgcn_mbcnt_hi((unsigned int)(mask >> 32),
           __builtin_amdgcn_mbcnt_lo((unsigned int)mask, 0u));
}

// ---- centrality = row-mean of memory bank (8 loads in flight) ----
__global__ __launch_bounds__(256)
void cent_kernel(const float* __restrict__ mem, float* __restrict__ cent, int M) {
    __shared__ float s[4];
    const int row = blockIdx.x;
    const float4* p = (const float4*)(mem + (size_t)row * M);
    const int n4 = M >> 2;
    float acc = 0.0f;
    int i = threadIdx.x;
    for (; i + 1792 < n4; i += 2048) {
        float4 q0 = p[i], q1 = p[i + 256], q2 = p[i + 512], q3 = p[i + 768];
        float4 q4 = p[i + 1024], q5 = p[i + 1280], q6 = p[i + 1536], q7 = p[i + 1792];
        acc += ((q0.x + q0.y) + (q0.z + q0.w)) + ((q1.x + q1.y) + (q1.z + q1.w))
             + ((q2.x + q2.y) + (q2.z + q2.w)) + ((q3.x + q3.y) + (q3.z + q3.w))
             + ((q4.x + q4.y) + (q4.z + q4.w)) + ((q5.x + q5.y) + (q5.z + q5.w))
             + ((q6.x + q6.y) + (q6.z + q6.w)) + ((q7.x + q7.y) + (q7.z + q7.w));
    }
    for (; i < n4; i += 256) {
        float4 q = p[i];
        acc += (q.x + q.y) + (q.z + q.w);
    }
    acc = wave_sum_f(acc);
    const int lane = threadIdx.x & 63, wid = threadIdx.x >> 6;
    if (lane == 0) s[wid] = acc;
    __syncthreads();
    if (threadIdx.x == 0) cent[row] = (s[0] + s[1] + s[2] + s[3]) / (float)M;
}

// ---- exact 64 smallest / 64 largest cent values (one block) ----
// list[r] = (float_bits(value) << 32) | index, r = exact rank.
__global__ __launch_bounds__(256)
void centlist_kernel(const float* __restrict__ cent,
                     unsigned long long* __restrict__ minlist,
                     unsigned long long* __restrict__ maxlist, int B) {
    __shared__ __align__(16) unsigned long long cand[256];
    __shared__ unsigned int s_cnt;
    const int tid = threadIdx.x;
    const float4* cp = (const float4*)cent;
    float4 v0 = cp[tid], v1 = cp[256 + tid], v2 = cp[512 + tid], v3 = cp[768 + tid];
    float vals[16] = {v0.x, v0.y, v0.z, v0.w, v1.x, v1.y, v1.z, v1.w,
                      v2.x, v2.y, v2.z, v2.w, v3.x, v3.y, v3.z, v3.w};

    for (int side = 0; side < 2; ++side) {
        unsigned int keys[16];
#pragma unroll
        for (int e = 0; e < 16; ++e) {
            const unsigned int kk = f_to_key(vals[e]);
            keys[e] = side ? kk : ~kk;      // side 0: inverted -> smallest first
        }
        // cent ~ N(0, 1/8192): +-0.0198 ~ z=1.79 -> E[cnt] ~ 150 each side
        unsigned int keyT = side ? f_to_key(0.0198f) : ~f_to_key(-0.0198f);
        unsigned int loK = 0u, hiK = 0xFFFFFFFFu, cnt = 0;
        for (int it = 0; it < MAXIT; ++it) {
            __syncthreads();
            if (tid == 0) s_cnt = 0;
            __syncthreads();
#pragma unroll
            for (int e = 0; e < 16; ++e) {
                if (keys[e] > keyT) {
                    const unsigned int pos = atomicAdd(&s_cnt, 1u);
                    if (pos < 256u) {
                        const unsigned int j =
                            (unsigned int)((e >> 2) * 1024 + tid * 4 + (e & 3));
                        cand[pos] = ((unsigned long long)keys[e] << 32) |
                                    (unsigned long long)(0xFFFFFFFFu - j);
                    }
                }
            }
            __syncthreads();
            cnt = s_cnt;
            if (cnt >= (unsigned int)NLIST && cnt <= 256u) break;
            if (cnt < (unsigned int)NLIST) { hiK = keyT; keyT = loK + ((keyT - loK) >> 1); }
            else                           { loK = keyT; keyT = keyT + ((hiK - keyT) >> 1); }
        }
        const unsigned int n = min(cnt, 256u);
        // block-wide exact all-pairs rank; rank < NLIST -> emit
        unsigned long long own = 0ull;
        if ((unsigned int)tid < n) own = cand[tid];
        unsigned int r = 0;
        for (unsigned int i = 0; i < n; ++i) r += (cand[i] > own) ? 1u : 0u;
        if ((unsigned int)tid < n && r < (unsigned int)NLIST) {
            const unsigned int kbits = (unsigned int)(own >> 32);
            const float val = key_to_f(side ? kbits : ~kbits);
            const unsigned int idx = 0xFFFFFFFFu - (unsigned int)own;
            (side ? maxlist : minlist)[r] =
                ((unsigned long long)__float_as_uint(val) << 32) |
                (unsigned long long)idx;
        }
        __syncthreads();
    }
}

// ---- per-row loss: ONE WAVE per row, 4 rows/block, no __syncthreads. ----
__global__ __launch_bounds__(256)
void row_loss_kernel(const float* __restrict__ sim,
                     const float* __restrict__ cent,
                     const unsigned long long* __restrict__ minlist,
                     const unsigned long long* __restrict__ maxlist,
                     const int* __restrict__ knn,
                     const float* __restrict__ temp_p,
                     float* __restrict__ per_row, int B) {
    __shared__ __align__(16) unsigned long long cand[4][CAPW];  // per-wave
    __shared__ __align__(16) unsigned long long ssel[4][64];    // per-wave
    __shared__ unsigned int bm[4][128];                         // 4096-bit/wave

    const int tid = threadIdx.x, lane = tid & 63, wid = tid >> 6;
    const int row = (blockIdx.x << 2) + wid;
    const int   k    = knn[0];
    const float temp = temp_p[0];
    const unsigned int uk = (unsigned int)k, need = uk + 1u;

    const float4* rp = (const float4*)(sim + (size_t)row * B);
    unsigned long long* mycand = cand[wid];
    unsigned long long* mysel  = ssel[wid];
    unsigned int*       mybm   = bm[wid];

    float dval;
    unsigned int kmin, wcnt;

    // sim-only stream pass: threshold gather into the wave segment,
    // row-min key, diag. 16 float4/lane, two 8-deep bursts.
    auto pass = [&](unsigned int kT, bool wr) {
        kmin = 0xFFFFFFFFu; dval = -INFINITY; wcnt = 0u;
        for (int g = 0; g < 2; ++g) {
            float4 sv[8];
#pragma unroll
            for (int u = 0; u < 8; ++u) sv[u] = rp[(g * 8 + u) * 64 + lane];
#pragma unroll
            for (int u = 0; u < 8; ++u) {
                const float tv[4] = {sv[u].x, sv[u].y, sv[u].z, sv[u].w};
#pragma unroll
                for (int m = 0; m < 4; ++m) {
                    const int j = (g * 8 + u) * 256 + lane * 4 + m;
                    unsigned int key = f_to_key(tv[m]);
                    const bool isd = (j == row);
                    if (isd) { dval = tv[m]; key = 0u; }
                    else if (key < kmin) kmin = key;
                    const bool p = (key > kT);
                    const unsigned long long mask = __ballot(p);
                    if (p && wr) {
                        const unsigned int pos = wcnt + lane_prefix(mask);
                        if (pos < CAPW)
                            mycand[pos] = ((unsigned long long)key << 32) |
                                (unsigned long long)(0xFFFFFFFFu - (unsigned int)j);
                    }
                    wcnt += (unsigned int)__popcll(mask);
                }
            }
        }
    };

    unsigned int keyT = f_to_key(2.2f);
    pass(keyT, true);
    unsigned int n = wcnt;                    // wave-uniform
    if (n < need || n > CAPW) {               // rare exact fallback (~5e-4/row)
        unsigned int loK = 0u, hiK = 0xFFFFFFFFu;
        for (int it = 0; it < MAXIT; ++it) {
            if (n < need) { hiK = keyT; keyT = loK + ((keyT - loK) >> 1); }
            else          { loK = keyT; keyT = keyT + ((hiK - keyT) >> 1); }
            pass(keyT, false);
            n = wcnt;
            if (n >= need && n <= CAPW) break;
        }
        pass(keyT, true);
        n = wcnt;
        if (n > CAPW) n = CAPW;               // statistical impossibility guard
    }

    const unsigned int kminb = wave_min_u32(kmin);
    const float sdiag = wave_max_f(dval);

    // clear exclusion bitmap (128 words / 64 lanes)
    mybm[lane] = 0u; mybm[lane + 64] = 0u;
    __builtin_amdgcn_wave_barrier();          // cand+bm writes ordered below

    // ---- in-wave exact all-pairs rank (n <= CAPW), fully unrolled b128 ----
    unsigned long long own = mycand[lane];    // stale if lane>=n (masked below)
    unsigned long long own2 = 0ull;
    unsigned int r = 0, r2 = 0;
    const ulonglong2* c2 = (const ulonglong2*)mycand;
    if (n <= 64u) {
#pragma unroll
        for (int o = 0; o < 32; ++o) {
            const ulonglong2 pr = c2[o];
            if ((unsigned int)(2 * o)     < n && pr.x > own) ++r;
            if ((unsigned int)(2 * o + 1) < n && pr.y > own) ++r;
        }
    } else {
        own2 = mycand[64 + lane];
#pragma unroll
        for (int o = 0; o < 64; ++o) {
            const ulonglong2 pr = c2[o];
            if ((unsigned int)(2 * o) < n) {
                if (pr.x > own)  ++r;
                if (pr.x > own2) ++r2;
            }
            if ((unsigned int)(2 * o + 1) < n) {
                if (pr.y > own)  ++r;
                if (pr.y > own2) ++r2;
            }
        }
    }

    // selected -> mysel + exclusion bits; rank==k -> p33
    unsigned int p33k = 0u;
    if ((unsigned int)lane < n) {
        if (r < uk) {
            mysel[r] = own;
            const unsigned int jj = 0xFFFFFFFFu - (unsigned int)own;
            atomicOr(&mybm[jj >> 5], 1u << (jj & 31));
        } else if (r == uk) p33k = (unsigned int)(own >> 32);
    }
    if (n > 64u) {
        const unsigned int t2 = (unsigned int)lane + 64u;
        if (t2 < n) {
            if (r2 < uk) {
                mysel[r2] = own2;
                const unsigned int jj = 0xFFFFFFFFu - (unsigned int)own2;
                atomicOr(&mybm[jj >> 5], 1u << (jj & 31));
            } else if (r2 == uk) p33k = (unsigned int)(own2 >> 32);
        }
    }
    if (lane == 0) atomicOr(&mybm[((unsigned int)row) >> 5], 1u << (row & 31));
    p33k = wave_max_u32(p33k);
    __builtin_amdgcn_wave_barrier();          // mysel/bm writes before reads

    // ---- mn_c/mx_c from precomputed order statistics (exact) ----
    float mnv, mxv;
    {
        const unsigned long long eMin = minlist[lane];
        const unsigned long long eMax = maxlist[lane];
        const unsigned int iMin = (unsigned int)eMin, iMax = (unsigned int)eMax;
        const float vMin = __uint_as_float((unsigned int)(eMin >> 32));
        const float vMax = __uint_as_float((unsigned int)(eMax >> 32));
        const bool exMin = (mybm[iMin >> 5] >> (iMin & 31)) & 1u;
        const bool exMax = (mybm[iMax >> 5] >> (iMax & 31)) & 1u;
        mnv = exMin ? INFINITY : vMin;
        mxv = exMax ? -INFINITY : vMax;
    }
    const float mn_c = wave_min_f(mnv);
    const float mx_c = wave_max_f(mxv);
    const float mn_s = key_to_f(kminb);
    const float mx_s = key_to_f(p33k);

    // ---- finale (math identical to validated v7/v8) ----
    const bool act = (lane < k);
    const unsigned long long sel = act ? mysel[lane] : 0ull;
    const float sj = act ? key_to_f((unsigned int)(sel >> 32)) : -INFINITY;
    const int   j  = act ? (int)(0xFFFFFFFFu - (unsigned int)sel) : 0;
    const float cj = cent[j];

    float a = -INFINITY;
    if (act) {
        const float ns = (sj - mn_s) / (mx_s - mn_s);
        const float nc = (cj - mn_c) / (mx_c - mn_c);
        a = (ns - nc) * temp;
    }
    const float am   = wave_max_f(a);
    const float e    = act ? expf(a - am) : 0.0f;
    const float esum = wave_sum_f(e);
    const float pw   = e / esum;

    // m2 = max(sj) = rank-0 candidate (exact, order-free max)
    const float m2  = fmaxf(key_to_f((unsigned int)(mysel[0] >> 32)), sdiag);
    const float ex  = act ? expf(sj - m2) : 0.0f;
    const float lse = m2 + logf(wave_sum_f(ex) + expf(sdiag - m2));

    const float num = wave_sum_f(act ? pw * (sj - lse) : 0.0f) + (sdiag - lse);
    const float den = 1.0f + wave_sum_f(pw);
    if (lane == 0) per_row[row] = -num / den;
}

// ---- final mean over per_row -> out[0] ----
__global__ __launch_bounds__(256)
void reduce_kernel(const float* __restrict__ per_row, float* __restrict__ out, int B) {
    __shared__ float s[4];
    float acc = 0.0f;
    const float4* p = (const float4*)per_row;
    const int n4 = B >> 2;
    for (int i = threadIdx.x; i < n4; i += 256) {
        float4 q = p[i];
        acc += (q.x + q.y) + (q.z + q.w);
    }
    acc = wave_sum_f(acc);
    const int lane = threadIdx.x & 63, wid = threadIdx.x >> 6;
    if (lane == 0) s[wid] = acc;
    __syncthreads();
    if (threadIdx.x == 0) out[0] = (s[0] + s[1] + s[2] + s[3]) / (float)B;
}

extern "C" void kernel_launch(void* const* d_in, const int* in_sizes, int n_in,
                              void* d_out, int out_size, void* d_ws, size_t ws_size,
                              hipStream_t stream) {
    const float* sim  = (const float*)d_in[0];
    const float* mem  = (const float*)d_in[1];
    const int*   knn  = (const int*)d_in[2];
    const float* temp = (const float*)d_in[3];
    float* out = (float*)d_out;

    char* ws = (char*)d_ws;
    float*              cent    = (float*)ws;                          // 16 KB
    float*              per_row = (float*)(ws + 16384);                // 16 KB
    unsigned long long* minlist = (unsigned long long*)(ws + 32768);   // 512 B
    unsigned long long* maxlist = (unsigned long long*)(ws + 33280);   // 512 B

    const int B = (int)(std::sqrt((double)in_sizes[0]) + 0.5);
    const int M = in_sizes[1] / B;

    cent_kernel<<<B, 256, 0, stream>>>(mem, cent, M);
    centlist_kernel<<<1, 256, 0, stream>>>(cent, minlist, maxlist, B);
    row_loss_kernel<<<B / 4, 256, 0, stream>>>(sim, cent, minlist, maxlist,
                                               knn, temp, per_row, B);
    reduce_kernel<<<1, 256, 0, stream>>>(per_row, out, B);
}